// Round 12
// baseline (290.710 us; speedup 1.0000x reference)
//
#include <hip/hip_runtime.h>
#include <hip/hip_bf16.h>
#include <math.h>
#include <stdint.h>

#define NTOK 21824

typedef __attribute__((ext_vector_type(8)))  short bf16x8;
typedef __attribute__((ext_vector_type(4)))  float f32x4;
typedef __attribute__((ext_vector_type(16))) float f32x16;

__device__ __forceinline__ uint32_t f2bf(float f) {
    uint32_t u = __builtin_bit_cast(uint32_t, f);
    return (u + 0x7FFFu + ((u >> 16) & 1u)) >> 16;   // RNE
}
__device__ __forceinline__ uint32_t pkbf2(float lo, float hi) {
    __hip_bfloat162 h = __float22bfloat162_rn(float2{lo, hi});
    uint32_t r; __builtin_memcpy(&r, &h, 4);         // v_cvt_pk_bf16_f32
    return r;
}

// ws layout (uint16): cls_Wh @0, box_Wh @65536, cls_Wo @131072, box_Wo(pad 16x256) @151552,
// hidden buffer @155648 (nb batches x NTOK x 512 bf16)
#define WOFF_CWH 0
#define WOFF_BWH 65536
#define WOFF_CWO 131072
#define WOFF_BWO 151552
#define HID_OFF  155648

__global__ void prep_weights(const float* __restrict__ cWh, const float* __restrict__ cWo,
                             const float* __restrict__ bWh, const float* __restrict__ bWo,
                             uint16_t* __restrict__ ws) {
    int i = blockIdx.x * 256 + threadIdx.x;
    if (i >= 155648) return;
    uint32_t v;
    if (i < 65536)       v = f2bf(cWh[i]);
    else if (i < 131072) v = f2bf(bWh[i - 65536]);
    else if (i < 151552) v = f2bf(cWo[i - 131072]);
    else { int j = i - 151552; v = (j < 1024) ? f2bf(bWo[j]) : 0u; }
    ws[i] = (uint16_t)v;
}

__device__ __forceinline__ void level_lookup(
    int n0, const float* fm0, const float* fm1, const float* fm2,
    const float* fm3, const float* fm4, const float*& fm, int& off, int& ls) {
    if      (n0 < 16384) { fm = fm0; off = 0;     ls = 7; }
    else if (n0 < 20480) { fm = fm1; off = 16384; ls = 6; }
    else if (n0 < 21504) { fm = fm2; off = 20480; ls = 5; }
    else if (n0 < 21760) { fm = fm3; off = 21504; ls = 4; }
    else                 { fm = fm4; off = 21760; ls = 3; }
}

// ======================= k1: X -> hidden (G1, both heads) =======================
__global__ __launch_bounds__(512, 4) void dfd_g1(
    const float* __restrict__ fm0, const float* __restrict__ fm1,
    const float* __restrict__ fm2, const float* __restrict__ fm3,
    const float* __restrict__ fm4,
    const float* __restrict__ cls_bh, const float* __restrict__ box_bh,
    const uint16_t* __restrict__ wbf,
    uint16_t* __restrict__ hid,     // [nb][NTOK][512] bf16 (chunk-local batches)
    int b0)
{
    __shared__ uint16_t Xs[64 * 256];   // [t][f^sw], sw = (t&7)<<3

    const int tid  = threadIdx.x;
    const int lane = tid & 63;
    const int w    = tid >> 6;          // wave 0..7
    const int col  = lane & 31;
    const int hi   = lane >> 5;
    const int n0   = blockIdx.x * 64;
    const int lb   = blockIdx.y;        // chunk-local batch
    const int b    = b0 + lb;           // global batch

    const float* fm; int off, ls;
    level_lookup(n0, fm0, fm1, fm2, fm3, fm4, fm, off, ls);
    const int hw = 1 << (2 * ls);
    const int p0 = n0 - off;

    // ---- stage: fm[b][f][p0+t] -> Xs[t][f^sw], packed b128 writes
    {
        const int t  = lane;
        const int sw = (t & 7) << 3;
        const float* src = fm + (size_t)b * 256 * hw + p0 + t;
        #pragma unroll
        for (int i = 0; i < 4; ++i) {
            const int f0 = w * 8 + i * 64;
            float x[8];
            #pragma unroll
            for (int e = 0; e < 8; ++e) x[e] = src[(size_t)(f0 + e) * hw];
            uint4 pk;
            pk.x = pkbf2(x[0], x[1]); pk.y = pkbf2(x[2], x[3]);
            pk.z = pkbf2(x[4], x[5]); pk.w = pkbf2(x[6], x[7]);
            *reinterpret_cast<uint4*>(&Xs[t * 256 + (f0 ^ sw)]) = pk;
        }
    }
    __syncthreads();    // the only barrier in k1

    // ---- G1 (32x32x16): C[h][t]. Wave w owns hh in [w*64, w*64+64)
    //      (hh<256 = cls hidden, hh>=256 = box hidden). Verified math.
    f32x16 acc[2][2];   // [mt = hh 32-tile][nt = token 32-tile]
    #pragma unroll
    for (int mt = 0; mt < 2; ++mt)
        #pragma unroll
        for (int nt = 0; nt < 2; ++nt)
            #pragma unroll
            for (int e = 0; e < 16; ++e) acc[mt][nt][e] = 0.f;

    const int hh0 = w * 64;
    const uint16_t* Wbase = (w < 4) ? wbf + WOFF_CWH + hh0 * 256
                                    : wbf + WOFF_BWH + (hh0 - 256) * 256;
    const int kh = hi * 8;
    const uint16_t* Wr = Wbase + col * 256 + kh;
    const int sw0 = (col & 7) << 3;

    #pragma unroll
    for (int ks = 0; ks < 16; ++ks) {
        const bf16x8 a0 = *(const bf16x8*)(Wr + ks * 16);
        const bf16x8 a1 = *(const bf16x8*)(Wr + 8192 + ks * 16);
        const int kx = (ks * 16 + kh) ^ sw0;
        const bf16x8 x0 = *(const bf16x8*)&Xs[col * 256 + kx];
        const bf16x8 x1 = *(const bf16x8*)&Xs[(32 + col) * 256 + kx];
        acc[0][0] = __builtin_amdgcn_mfma_f32_32x32x16_bf16(a0, x0, acc[0][0], 0, 0, 0);
        acc[0][1] = __builtin_amdgcn_mfma_f32_32x32x16_bf16(a0, x1, acc[0][1], 0, 0, 0);
        acc[1][0] = __builtin_amdgcn_mfma_f32_32x32x16_bf16(a1, x0, acc[1][0], 0, 0, 0);
        acc[1][1] = __builtin_amdgcn_mfma_f32_32x32x16_bf16(a1, x1, acc[1][1], 0, 0, 0);
    }

    // ---- epilogue: bias+ReLU, write hidden to global.
    //      Wave w covers hh0..hh0+63 = exactly one 128B line per token.
    const float* bh_ = (w < 4) ? cls_bh + hh0 : box_bh + (hh0 - 256);
    #pragma unroll
    for (int nt = 0; nt < 2; ++nt) {
        const int t = nt * 32 + col;
        uint16_t* hrow = hid + ((size_t)lb * NTOK + n0 + t) * 512 + hh0;
        #pragma unroll
        for (int mt = 0; mt < 2; ++mt) {
            #pragma unroll
            for (int g = 0; g < 4; ++g) {
                const int hb = mt * 32 + 8 * g + 4 * hi;   // hidden idx = hh0+hb+(0..3)
                const f32x4 bv = *(const f32x4*)(bh_ + hb);
                const float v0 = fmaxf(acc[mt][nt][4 * g + 0] + bv[0], 0.f);
                const float v1 = fmaxf(acc[mt][nt][4 * g + 1] + bv[1], 0.f);
                const float v2 = fmaxf(acc[mt][nt][4 * g + 2] + bv[2], 0.f);
                const float v3 = fmaxf(acc[mt][nt][4 * g + 3] + bv[3], 0.f);
                uint2 pk; pk.x = pkbf2(v0, v1); pk.y = pkbf2(v2, v3);
                *reinterpret_cast<uint2*>(hrow + hb) = pk;
            }
        }
    }
}

// ======================= k2: hidden -> output (G2 + decode) =======================
__global__ __launch_bounds__(256, 6) void dfd_g2(
    const float* __restrict__ cls_bo, const float* __restrict__ box_bo,
    const uint16_t* __restrict__ wbf,
    const uint16_t* __restrict__ hid,
    float* __restrict__ out,
    int b0)
{
    const int tid  = threadIdx.x;
    const int lane = tid & 63;
    const int w    = tid >> 6;          // wave 0..3, each owns 16 tokens
    const int r    = lane & 15;
    const int q    = lane >> 4;
    const int n0   = blockIdx.x * 64;
    const int lb   = blockIdx.y;
    const int b    = b0 + lb;
    const int t0   = n0 + w * 16;       // first token of this wave

    int off, ls; const float* fm_unused;
    level_lookup(n0, nullptr, nullptr, nullptr, nullptr, nullptr, fm_unused, off, ls);
    const int dim = 1 << ls;
    const int p0  = n0 - off;

    // C[out][tok]: A = Wo rows (out), B = hidden (k-contiguous per token, from L3)
    f32x4 c[6];
    #pragma unroll
    for (int m = 0; m < 6; ++m) c[m] = {0.f, 0.f, 0.f, 0.f};

    const uint16_t* hrow = hid + ((size_t)lb * NTOK + t0 + r) * 512 + q * 8;
    const uint16_t* WoA  = wbf + WOFF_CWO + r * 256 + q * 8;
    const uint16_t* WoB  = wbf + WOFF_BWO + r * 256 + q * 8;

    #pragma unroll
    for (int kq = 0; kq < 8; ++kq) {
        const bf16x8 hbc = *(const bf16x8*)(hrow + kq * 32);          // cls hidden
        const bf16x8 hbb = *(const bf16x8*)(hrow + 256 + kq * 32);    // box hidden
        #pragma unroll
        for (int m = 0; m < 5; ++m) {
            const bf16x8 a = *(const bf16x8*)(WoA + m * 4096 + kq * 32);
            c[m] = __builtin_amdgcn_mfma_f32_16x16x32_bf16(a, hbc, c[m], 0, 0, 0);
        }
        const bf16x8 ab = *(const bf16x8*)(WoB + kq * 32);
        c[5] = __builtin_amdgcn_mfma_f32_16x16x32_bf16(ab, hbb, c[5], 0, 0, 0);
    }

    // ---- stores: one wave writes all 84 outs of its 16 tokens in one burst.
    //      D mapping: col = r (token), row = q*4+jj (out within tile).
    float* orow = out + ((size_t)b * NTOK + t0 + r) * 84;
    #pragma unroll
    for (int m = 0; m < 5; ++m) {
        const f32x4 bo = *(const f32x4*)(cls_bo + m * 16 + q * 4);
        f32x4 v;
        #pragma unroll
        for (int jj = 0; jj < 4; ++jj) v[jj] = c[m][jj] + bo[jj];
        *(f32x4*)(orow + m * 16 + q * 4) = v;
    }
    if (q == 0) {   // box rows 0..3 (padded Wo rows 4..15 are zero)
        const f32x4 bo = *(const f32x4*)box_bo;
        const float inv = 1.0f / (float)dim;
        const int p = p0 + w * 16 + r;
        const float d0 = tanhf(c[5][0] + bo[0]);
        const float d1 = tanhf(c[5][1] + bo[1]);
        const float d2 = tanhf(c[5][2] + bo[2]);
        const float d3 = tanhf(c[5][3] + bo[3]);
        f32x4 v;
        v[0] = ((float)(p & (dim - 1)) + 0.5f) * inv + 0.1f * d0;
        v[1] = ((float)(p >> ls) + 0.5f) * inv + 0.1f * d1;
        v[2] = exp2f(d2) * inv;
        v[3] = exp2f(d3) * inv;
        *(f32x4*)(orow + 80) = v;
    }
}

// ======================= fallback: round-10 fused kernel =======================
__global__ __launch_bounds__(512, 4) void dfd_fused(
    const float* __restrict__ fm0, const float* __restrict__ fm1,
    const float* __restrict__ fm2, const float* __restrict__ fm3,
    const float* __restrict__ fm4,
    const float* __restrict__ cls_bh, const float* __restrict__ cls_bo,
    const float* __restrict__ box_bh, const float* __restrict__ box_bo,
    const uint16_t* __restrict__ wbf,
    float* __restrict__ out)
{
    __shared__ uint16_t LB[64 * 512];
    uint16_t* Xs = LB;
    uint16_t* Hs = LB;

    const int tid  = threadIdx.x;
    const int lane = tid & 63;
    const int w    = tid >> 6;
    const int r    = lane & 15;
    const int q    = lane >> 4;
    const int col  = lane & 31;
    const int hi   = lane >> 5;
    const int n0   = blockIdx.x * 64;
    const int b    = blockIdx.y;

    const float* fm; int off, ls;
    level_lookup(n0, fm0, fm1, fm2, fm3, fm4, fm, off, ls);
    const int dim = 1 << ls;
    const int hw  = 1 << (2 * ls);
    const int p0  = n0 - off;

    {
        const int t  = lane;
        const int sw = (t & 7) << 3;
        const float* src = fm + (size_t)b * 256 * hw + p0 + t;
        #pragma unroll
        for (int i = 0; i < 4; ++i) {
            const int f0 = w * 8 + i * 64;
            float x[8];
            #pragma unroll
            for (int e = 0; e < 8; ++e) x[e] = src[(size_t)(f0 + e) * hw];
            uint4 pk;
            pk.x = pkbf2(x[0], x[1]); pk.y = pkbf2(x[2], x[3]);
            pk.z = pkbf2(x[4], x[5]); pk.w = pkbf2(x[6], x[7]);
            *reinterpret_cast<uint4*>(&Xs[t * 256 + (f0 ^ sw)]) = pk;
        }
    }
    __syncthreads();

    f32x16 acc[2][2];
    {
        #pragma unroll
        for (int mt = 0; mt < 2; ++mt)
            #pragma unroll
            for (int nt = 0; nt < 2; ++nt)
                #pragma unroll
                for (int e = 0; e < 16; ++e) acc[mt][nt][e] = 0.f;

        const int hh0 = w * 64;
        const uint16_t* Wbase = (w < 4) ? wbf + WOFF_CWH + hh0 * 256
                                        : wbf + WOFF_BWH + (hh0 - 256) * 256;
        const int kh = hi * 8;
        const uint16_t* Wr = Wbase + col * 256 + kh;
        const int sw0 = (col & 7) << 3;

        #pragma unroll
        for (int ks = 0; ks < 16; ++ks) {
            const bf16x8 a0 = *(const bf16x8*)(Wr + ks * 16);
            const bf16x8 a1 = *(const bf16x8*)(Wr + 8192 + ks * 16);
            const int kx = (ks * 16 + kh) ^ sw0;
            const bf16x8 x0 = *(const bf16x8*)&Xs[col * 256 + kx];
            const bf16x8 x1 = *(const bf16x8*)&Xs[(32 + col) * 256 + kx];
            acc[0][0] = __builtin_amdgcn_mfma_f32_32x32x16_bf16(a0, x0, acc[0][0], 0, 0, 0);
            acc[0][1] = __builtin_amdgcn_mfma_f32_32x32x16_bf16(a0, x1, acc[0][1], 0, 0, 0);
            acc[1][0] = __builtin_amdgcn_mfma_f32_32x32x16_bf16(a1, x0, acc[1][0], 0, 0, 0);
            acc[1][1] = __builtin_amdgcn_mfma_f32_32x32x16_bf16(a1, x1, acc[1][1], 0, 0, 0);
        }
    }
    __syncthreads();

    {
        const int hh0 = w * 64;
        const float* bh_ = (w < 4) ? cls_bh + hh0 : box_bh + (hh0 - 256);
        #pragma unroll
        for (int mt = 0; mt < 2; ++mt) {
            #pragma unroll
            for (int nt = 0; nt < 2; ++nt) {
                const int t   = nt * 32 + col;
                const int swt = (t & 7) << 3;
                #pragma unroll
                for (int g = 0; g < 4; ++g) {
                    const int hb = mt * 32 + 8 * g + 4 * hi;
                    const f32x4 bv = *(const f32x4*)(bh_ + hb);
                    const float v0 = fmaxf(acc[mt][nt][4 * g + 0] + bv[0], 0.f);
                    const float v1 = fmaxf(acc[mt][nt][4 * g + 1] + bv[1], 0.f);
                    const float v2 = fmaxf(acc[mt][nt][4 * g + 2] + bv[2], 0.f);
                    const float v3 = fmaxf(acc[mt][nt][4 * g + 3] + bv[3], 0.f);
                    uint2 pk; pk.x = pkbf2(v0, v1); pk.y = pkbf2(v2, v3);
                    *reinterpret_cast<uint2*>(&Hs[t * 512 + ((hh0 + hb) ^ swt)]) = pk;
                }
            }
        }
    }
    __syncthreads();

    if (w < 5) {
        f32x4 c[4];
        #pragma unroll
        for (int m = 0; m < 4; ++m) c[m] = {0.f, 0.f, 0.f, 0.f};
        const uint16_t* Bw = wbf + WOFF_CWO + (w * 16 + r) * 256 + q * 8;
        #pragma unroll
        for (int kq = 0; kq < 8; ++kq) {
            const bf16x8 bfr = *(const bf16x8*)(Bw + kq * 32);
            #pragma unroll
            for (int m = 0; m < 4; ++m) {
                const int t = m * 16 + r;
                const int kcol = (kq * 32 + q * 8) ^ ((t & 7) << 3);
                const bf16x8 a = *(const bf16x8*)&Hs[t * 512 + kcol];
                c[m] = __builtin_amdgcn_mfma_f32_16x16x32_bf16(a, bfr, c[m], 0, 0, 0);
            }
        }
        const float bo_l = cls_bo[w * 16 + r];
        #pragma unroll
        for (int m = 0; m < 4; ++m)
            #pragma unroll
            for (int jj = 0; jj < 4; ++jj)
                out[((size_t)b * NTOK + n0 + m * 16 + q * 4 + jj) * 84 + w * 16 + r]
                    = c[m][jj] + bo_l;
    } else if (w < 7) {
        const int m0 = (w - 5) * 2;
        f32x4 c[2];
        c[0] = {0.f, 0.f, 0.f, 0.f}; c[1] = {0.f, 0.f, 0.f, 0.f};
        const uint16_t* Bw = wbf + WOFF_BWO + r * 256 + q * 8;
        #pragma unroll
        for (int kq = 0; kq < 8; ++kq) {
            const bf16x8 bfr = *(const bf16x8*)(Bw + kq * 32);
            #pragma unroll
            for (int mm = 0; mm < 2; ++mm) {
                const int t = (m0 + mm) * 16 + r;
                const int kcol = 256 + ((kq * 32 + q * 8) ^ ((t & 7) << 3));
                const bf16x8 a = *(const bf16x8*)&Hs[t * 512 + kcol];
                c[mm] = __builtin_amdgcn_mfma_f32_16x16x32_bf16(a, bfr, c[mm], 0, 0, 0);
            }
        }
        if (r < 4) {
            const float bo_l = box_bo[r];
            const float inv  = 1.0f / (float)dim;
            #pragma unroll
            for (int mm = 0; mm < 2; ++mm)
                #pragma unroll
                for (int jj = 0; jj < 4; ++jj) {
                    const int t = (m0 + mm) * 16 + q * 4 + jj;
                    const int p = p0 + t;
                    const float d = tanhf(c[mm][jj] + bo_l);
                    float val;
                    if (r == 0)      val = ((float)(p & (dim - 1)) + 0.5f) * inv + 0.1f * d;
                    else if (r == 1) val = ((float)(p >> ls) + 0.5f) * inv + 0.1f * d;
                    else             val = exp2f(d) * inv;
                    out[((size_t)b * NTOK + n0 + t) * 84 + 80 + r] = val;
                }
        }
    }
}

extern "C" void kernel_launch(void* const* d_in, const int* in_sizes, int n_in,
                              void* d_out, int out_size, void* d_ws, size_t ws_size,
                              hipStream_t stream) {
    uint16_t* ws = (uint16_t*)d_ws;
    prep_weights<<<608, 256, 0, stream>>>(
        (const float*)d_in[5],  (const float*)d_in[7],
        (const float*)d_in[9],  (const float*)d_in[11], ws);

    const size_t HID_B_PER_BATCH = (size_t)NTOK * 512 * 2;   // 22,347,776 B
    const size_t W_BYTES = (size_t)HID_OFF * 2;
    int nb = 0;
    if      (ws_size >= W_BYTES + 4 * HID_B_PER_BATCH) nb = 4;   // L3-resident sweet spot
    else if (ws_size >= W_BYTES + 2 * HID_B_PER_BATCH) nb = 2;
    else if (ws_size >= W_BYTES + 1 * HID_B_PER_BATCH) nb = 1;

    if (nb > 0) {
        uint16_t* hid = ws + HID_OFF;
        for (int b0 = 0; b0 < 8; b0 += nb) {
            dim3 g(NTOK / 64, nb);
            dfd_g1<<<g, 512, 0, stream>>>(
                (const float*)d_in[0], (const float*)d_in[1], (const float*)d_in[2],
                (const float*)d_in[3], (const float*)d_in[4],
                (const float*)d_in[6], (const float*)d_in[10],
                ws, hid, b0);
            dfd_g2<<<g, 256, 0, stream>>>(
                (const float*)d_in[8], (const float*)d_in[12],
                ws, hid, (float*)d_out, b0);
        }
    } else {
        dim3 grid(NTOK / 64, 8);
        dfd_fused<<<grid, 512, 0, stream>>>(
            (const float*)d_in[0], (const float*)d_in[1], (const float*)d_in[2],
            (const float*)d_in[3], (const float*)d_in[4],
            (const float*)d_in[6],  (const float*)d_in[8],
            (const float*)d_in[10], (const float*)d_in[12],
            ws, (float*)d_out);
    }
}

// Round 13
// 263.189 us; speedup vs baseline: 1.1046x; 1.1046x over previous
//
#include <hip/hip_runtime.h>
#include <hip/hip_bf16.h>
#include <math.h>
#include <stdint.h>

#define NTOK 21824

typedef __attribute__((ext_vector_type(8)))  short bf16x8;
typedef __attribute__((ext_vector_type(4)))  float f32x4;
typedef __attribute__((ext_vector_type(16))) float f32x16;

__device__ __forceinline__ uint32_t f2bf(float f) {
    uint32_t u = __builtin_bit_cast(uint32_t, f);
    return (u + 0x7FFFu + ((u >> 16) & 1u)) >> 16;   // RNE
}
__device__ __forceinline__ uint32_t pkbf2(float lo, float hi) {
    __hip_bfloat162 h = __float22bfloat162_rn(float2{lo, hi});
    uint32_t r; __builtin_memcpy(&r, &h, 4);         // v_cvt_pk_bf16_f32
    return r;
}

// ws layout (uint16): cls_Wh @0, box_Wh @65536, cls_Wo @131072, box_Wo(pad 16x256) @151552
#define WOFF_CWH 0
#define WOFF_BWH 65536
#define WOFF_CWO 131072
#define WOFF_BWO 151552

__global__ void prep_weights(const float* __restrict__ cWh, const float* __restrict__ cWo,
                             const float* __restrict__ bWh, const float* __restrict__ bWo,
                             uint16_t* __restrict__ ws) {
    int i = blockIdx.x * 256 + threadIdx.x;
    if (i >= 155648) return;
    uint32_t v;
    if (i < 65536)       v = f2bf(cWh[i]);
    else if (i < 131072) v = f2bf(bWh[i - 65536]);
    else if (i < 151552) v = f2bf(cWo[i - 131072]);
    else { int j = i - 151552; v = (j < 1024) ? f2bf(bWo[j]) : 0u; }
    ws[i] = (uint16_t)v;
}

// 4-wave / 32-token fused block: 32 KB LDS -> 4 independent barrier groups per CU.
__global__ __launch_bounds__(256, 4) void dfd_fused(
    const float* __restrict__ fm0, const float* __restrict__ fm1,
    const float* __restrict__ fm2, const float* __restrict__ fm3,
    const float* __restrict__ fm4,
    const float* __restrict__ cls_bh, const float* __restrict__ cls_bo,
    const float* __restrict__ box_bh, const float* __restrict__ box_bo,
    const uint16_t* __restrict__ wbf,
    float* __restrict__ out)
{
    // 32 KB overlay: Xs[32 t][256 f] (phase 1-2) then Hs[32 t][512 hh] (phase 3-4)
    __shared__ uint16_t LB[32 * 512];
    uint16_t* Xs = LB;
    uint16_t* Hs = LB;

    const int tid  = threadIdx.x;
    const int lane = tid & 63;
    const int w    = tid >> 6;          // wave 0..3
    const int r    = lane & 15;
    const int q    = lane >> 4;
    const int col  = lane & 31;
    const int hi   = lane >> 5;
    const int n0   = blockIdx.x * 32;   // 32-token tile (level offsets all /32)
    const int b    = blockIdx.y;

    const float* fm; int off, ls;
    if      (n0 < 16384) { fm = fm0; off = 0;     ls = 7; }
    else if (n0 < 20480) { fm = fm1; off = 16384; ls = 6; }
    else if (n0 < 21504) { fm = fm2; off = 20480; ls = 5; }
    else if (n0 < 21760) { fm = fm3; off = 21504; ls = 4; }
    else                 { fm = fm4; off = 21760; ls = 3; }
    const int dim = 1 << ls;
    const int hw  = 1 << (2 * ls);
    const int p0  = n0 - off;

    // ---- stage: fm[b][f][p0+t] -> Xs[t][f^sw] bf16, packed b128 writes.
    //      thread: t = tid&31, fgroup = tid>>5 covers 32 features.
    {
        const int t  = tid & 31;
        const int fg = tid >> 5;            // 0..7
        const int sw = (t & 7) << 3;
        const float* src = fm + (size_t)b * 256 * hw + p0 + t;
        #pragma unroll
        for (int i = 0; i < 4; ++i) {
            const int f0 = fg * 32 + i * 8;   // 8 consecutive features, 8-aligned
            float x[8];
            #pragma unroll
            for (int e = 0; e < 8; ++e) x[e] = src[(size_t)(f0 + e) * hw];
            uint4 pk;
            pk.x = pkbf2(x[0], x[1]); pk.y = pkbf2(x[2], x[3]);
            pk.z = pkbf2(x[4], x[5]); pk.w = pkbf2(x[6], x[7]);
            *reinterpret_cast<uint4*>(&Xs[t * 256 + (f0 ^ sw)]) = pk;
        }
    }
    __syncthreads();

    // ---- G1 (32x32x16): C[h][t]. Wave w owns hh in [w*128, w*128+128) of the
    //      unified space (hh<256 = cls hidden, hh>=256 = box hidden).
    f32x16 acc[4];      // [mt]: hh 32-tile within the wave's 128-slice
    {
        #pragma unroll
        for (int mt = 0; mt < 4; ++mt)
            #pragma unroll
            for (int e = 0; e < 16; ++e) acc[mt][e] = 0.f;

        const uint16_t* Wbase = (w < 2) ? wbf + WOFF_CWH + (w * 128) * 256
                                        : wbf + WOFF_BWH + ((w - 2) * 128) * 256;
        const int kh = hi * 8;
        const uint16_t* Wr = Wbase + col * 256 + kh;   // A row = w*128 + mt*32 + col
        const int sw0 = (col & 7) << 3;

        #pragma unroll
        for (int ks = 0; ks < 16; ++ks) {
            const int kx = (ks * 16 + kh) ^ sw0;
            const bf16x8 x0 = *(const bf16x8*)&Xs[col * 256 + kx];
            #pragma unroll
            for (int mt = 0; mt < 4; ++mt) {
                const bf16x8 a = *(const bf16x8*)(Wr + mt * 8192 + ks * 16);
                acc[mt] = __builtin_amdgcn_mfma_f32_32x32x16_bf16(a, x0, acc[mt], 0, 0, 0);
            }
        }
    }
    __syncthreads();   // all Xs reads done before Hs overwrites

    // ---- epilogue: bias+ReLU, pack 4 consecutive hh per b64 write
    {
        const float* bh_ = (w < 2) ? cls_bh + w * 128 : box_bh + (w - 2) * 128;
        const int t   = col;
        const int swt = (t & 7) << 3;
        #pragma unroll
        for (int mt = 0; mt < 4; ++mt) {
            #pragma unroll
            for (int g = 0; g < 4; ++g) {
                const int hb = mt * 32 + 8 * g + 4 * hi;   // C row = hb + (reg&3)
                const f32x4 bv = *(const f32x4*)(bh_ + hb);
                const float v0 = fmaxf(acc[mt][4 * g + 0] + bv[0], 0.f);
                const float v1 = fmaxf(acc[mt][4 * g + 1] + bv[1], 0.f);
                const float v2 = fmaxf(acc[mt][4 * g + 2] + bv[2], 0.f);
                const float v3 = fmaxf(acc[mt][4 * g + 3] + bv[3], 0.f);
                uint2 pk; pk.x = pkbf2(v0, v1); pk.y = pkbf2(v2, v3);
                *reinterpret_cast<uint2*>(&Hs[t * 512 + ((w * 128 + hb) ^ swt)]) = pk;
            }
        }
    }
    __syncthreads();

    // ---- G2 (16x16x32): wave = (token-half th = w&1, out-set ms = w>>1)
    //      ms 0: cls tiles {0,1,2}; ms 1: cls tiles {3,4} + box + decode.
    {
        const int th = w & 1;
        const int ms = w >> 1;
        const int t  = th * 16 + r;                 // A row token (th*16 multiple of 8)
        const int swt = (r & 7) << 3;
        const uint16_t* hrow = &Hs[t * 512];
        const int m0 = ms * 3;                      // first cls tile

        f32x4 c[3];
        c[0] = {0.f,0.f,0.f,0.f}; c[1] = {0.f,0.f,0.f,0.f}; c[2] = {0.f,0.f,0.f,0.f};
        const uint16_t* WoA = wbf + WOFF_CWO + r * 256 + q * 8;
        const uint16_t* WoB = wbf + WOFF_BWO + r * 256 + q * 8;

        #pragma unroll
        for (int kq = 0; kq < 8; ++kq) {
            const int kcol = (kq * 32 + q * 8) ^ swt;
            const bf16x8 a = *(const bf16x8*)&hrow[kcol];          // cls hidden (A-frag)
            const bf16x8 b0 = *(const bf16x8*)(WoA + (m0 + 0) * 4096 + kq * 32);
            const bf16x8 b1 = *(const bf16x8*)(WoA + (m0 + 1) * 4096 + kq * 32);
            c[0] = __builtin_amdgcn_mfma_f32_16x16x32_bf16(a, b0, c[0], 0, 0, 0);
            c[1] = __builtin_amdgcn_mfma_f32_16x16x32_bf16(a, b1, c[1], 0, 0, 0);
            if (ms == 0) {
                const bf16x8 b2 = *(const bf16x8*)(WoA + 2 * 4096 + kq * 32);
                c[2] = __builtin_amdgcn_mfma_f32_16x16x32_bf16(a, b2, c[2], 0, 0, 0);
            } else {
                const bf16x8 ab = *(const bf16x8*)&hrow[256 + kcol];  // box hidden
                const bf16x8 b2 = *(const bf16x8*)(WoB + kq * 32);
                c[2] = __builtin_amdgcn_mfma_f32_16x16x32_bf16(ab, b2, c[2], 0, 0, 0);
            }
        }

        // stores: D row = token th*16 + q*4 + jj, D col = out-tile*16 + r
        const int ncls = (ms == 0) ? 3 : 2;
        #pragma unroll
        for (int i = 0; i < 3; ++i) {
            if (i < ncls) {
                const int m = m0 + i;
                const float bo_l = cls_bo[m * 16 + r];
                #pragma unroll
                for (int jj = 0; jj < 4; ++jj)
                    out[((size_t)b * NTOK + n0 + th * 16 + q * 4 + jj) * 84 + m * 16 + r]
                        = c[i][jj] + bo_l;
            }
        }
        if (ms == 1 && r < 4) {   // box rows 0..3 (padded Wo rows 4..15 are zero)
            const float bo_l = box_bo[r];
            const float inv  = 1.0f / (float)dim;
            #pragma unroll
            for (int jj = 0; jj < 4; ++jj) {
                const int t2 = th * 16 + q * 4 + jj;
                const int p  = p0 + t2;
                const float d = tanhf(c[2][jj] + bo_l);
                float val;
                if (r == 0)      val = ((float)(p & (dim - 1)) + 0.5f) * inv + 0.1f * d;
                else if (r == 1) val = ((float)(p >> ls) + 0.5f) * inv + 0.1f * d;
                else             val = exp2f(d) * inv;
                out[((size_t)b * NTOK + n0 + t2) * 84 + 80 + r] = val;
            }
        }
    }
}

extern "C" void kernel_launch(void* const* d_in, const int* in_sizes, int n_in,
                              void* d_out, int out_size, void* d_ws, size_t ws_size,
                              hipStream_t stream) {
    uint16_t* ws = (uint16_t*)d_ws;
    prep_weights<<<608, 256, 0, stream>>>(
        (const float*)d_in[5],  (const float*)d_in[7],
        (const float*)d_in[9],  (const float*)d_in[11], ws);
    dim3 grid(NTOK / 32, 8);   // 682 x 8 blocks, 256 threads, one 32-token tile each
    dfd_fused<<<grid, 256, 0, stream>>>(
        (const float*)d_in[0], (const float*)d_in[1], (const float*)d_in[2],
        (const float*)d_in[3], (const float*)d_in[4],
        (const float*)d_in[6],  (const float*)d_in[8],
        (const float*)d_in[10], (const float*)d_in[12],
        ws, (float*)d_out);
}

// Round 14
// 111.551 us; speedup vs baseline: 2.6061x; 2.3594x over previous
//
#include <hip/hip_runtime.h>
#include <hip/hip_bf16.h>
#include <math.h>
#include <stdint.h>

#define NTOK 21824
#define NTILE128 171     // 170 full 128-token tiles + 1 tail (64 tokens)

typedef __attribute__((ext_vector_type(8)))  short bf16x8;
typedef __attribute__((ext_vector_type(4)))  float f32x4;
typedef __attribute__((ext_vector_type(16))) float f32x16;

__device__ __forceinline__ uint32_t f2bf(float f) {
    uint32_t u = __builtin_bit_cast(uint32_t, f);
    return (u + 0x7FFFu + ((u >> 16) & 1u)) >> 16;   // RNE
}
__device__ __forceinline__ uint32_t pkbf2(float lo, float hi) {
    __hip_bfloat162 h = __float22bfloat162_rn(float2{lo, hi});
    uint32_t r; __builtin_memcpy(&r, &h, 4);         // v_cvt_pk_bf16_f32
    return r;
}

// ws layout (uint16): cls_Wh @0, box_Wh @65536, cls_Wo @131072, box_Wo(pad 16x256) @151552
#define WOFF_CWH 0
#define WOFF_BWH 65536
#define WOFF_CWO 131072
#define WOFF_BWO 151552

__global__ void prep_weights(const float* __restrict__ cWh, const float* __restrict__ cWo,
                             const float* __restrict__ bWh, const float* __restrict__ bWo,
                             uint16_t* __restrict__ ws) {
    int i = blockIdx.x * 256 + threadIdx.x;
    if (i >= 155648) return;
    uint32_t v;
    if (i < 65536)       v = f2bf(cWh[i]);
    else if (i < 131072) v = f2bf(bWh[i - 65536]);
    else if (i < 151552) v = f2bf(cWo[i - 131072]);
    else { int j = i - 151552; v = (j < 1024) ? f2bf(bWo[j]) : 0u; }
    ws[i] = (uint16_t)v;
}

// Head-split block: 128 tokens x ONE head (cls or box). 8 waves, 64 KB LDS overlay.
__global__ __launch_bounds__(512, 4) void dfd_head(
    const float* __restrict__ fm0, const float* __restrict__ fm1,
    const float* __restrict__ fm2, const float* __restrict__ fm3,
    const float* __restrict__ fm4,
    const float* __restrict__ cls_bh, const float* __restrict__ cls_bo,
    const float* __restrict__ box_bh, const float* __restrict__ box_bo,
    const uint16_t* __restrict__ wbf,
    float* __restrict__ out)
{
    // decode (tile, head) from group-of-16 swizzle: twins (s, s+8) share id%8 -> same XCD
    const int g    = blockIdx.x;
    const int s    = g & 15;
    const int tile = (g >> 4) * 8 + (s & 7);
    const int head = s >> 3;                 // 0 = cls, 1 = box
    if (tile >= NTILE128) return;            // block-uniform

    // 64 KB overlay: Xs[128 t][256 f] (phases 1-2) then Hs[128 t][256 hh] (phases 3-4)
    __shared__ uint16_t LB[128 * 256];
    uint16_t* Xs = LB;
    uint16_t* Hs = LB;

    const int tid  = threadIdx.x;
    const int lane = tid & 63;
    const int w    = tid >> 6;               // wave 0..7
    const int r    = lane & 15;
    const int q    = lane >> 4;
    const int col  = lane & 31;
    const int hi   = lane >> 5;
    const int n0   = tile * 128;
    const int b    = blockIdx.y;

    const float* fm; int off, ls;
    if      (n0 < 16384) { fm = fm0; off = 0;     ls = 7; }
    else if (n0 < 20480) { fm = fm1; off = 16384; ls = 6; }
    else if (n0 < 21504) { fm = fm2; off = 20480; ls = 5; }
    else if (n0 < 21760) { fm = fm3; off = 21504; ls = 4; }
    else                 { fm = fm4; off = 21760; ls = 3; }
    const int dim = 1 << ls;
    const int hw  = 1 << (2 * ls);
    const int p0  = n0 - off;
    const int T   = (n0 == 21760) ? 64 : 128;   // tail tile has 64 tokens
    const int NT16 = T >> 4;                    // active 16-token tiles in G2

    // ---- stage: fm[b][f][p0+t] -> Xs[t][f^sw] bf16, packed b128 writes
    {
        const int t  = tid & 127;
        const int fg = tid >> 7;             // 0..3, covers 64 features
        const int sw = (t & 7) << 3;
        if (t < T) {
            const float* src = fm + (size_t)b * 256 * hw + p0 + t;
            #pragma unroll
            for (int i = 0; i < 8; ++i) {
                const int f0 = fg * 64 + i * 8;
                float x[8];
                #pragma unroll
                for (int e = 0; e < 8; ++e) x[e] = src[(size_t)(f0 + e) * hw];
                uint4 pk;
                pk.x = pkbf2(x[0], x[1]); pk.y = pkbf2(x[2], x[3]);
                pk.z = pkbf2(x[4], x[5]); pk.w = pkbf2(x[6], x[7]);
                *reinterpret_cast<uint4*>(&Xs[t * 256 + (f0 ^ sw)]) = pk;
            }
        }
    }
    __syncthreads();

    // ---- G1 (32x32x16): C[h][t]. Wave w owns hh [w*32, w*32+32) of THIS head's 256.
    //      Weight slice (16 KB) read once per 128 tokens. (Tail: acc[2..3] garbage, unused.)
    f32x16 acc[4];   // [nt = token 32-tile]
    {
        #pragma unroll
        for (int nt = 0; nt < 4; ++nt)
            #pragma unroll
            for (int e = 0; e < 16; ++e) acc[nt][e] = 0.f;

        const int hhw = w * 32;
        const uint16_t* Wbase = wbf + (head ? WOFF_BWH : WOFF_CWH) + hhw * 256;
        const int kh = hi * 8;
        const uint16_t* Wr = Wbase + col * 256 + kh;   // A row = hhw + col
        const int sw0 = (col & 7) << 3;

        #pragma unroll
        for (int ks = 0; ks < 16; ++ks) {
            const bf16x8 a = *(const bf16x8*)(Wr + ks * 16);
            const int kx = (ks * 16 + kh) ^ sw0;
            #pragma unroll
            for (int nt = 0; nt < 4; ++nt) {
                const bf16x8 x = *(const bf16x8*)&Xs[(nt * 32 + col) * 256 + kx];
                acc[nt] = __builtin_amdgcn_mfma_f32_32x32x16_bf16(a, x, acc[nt], 0, 0, 0);
            }
        }
    }
    __syncthreads();   // all Xs reads done before Hs overwrites

    // ---- epilogue: bias+ReLU, pack 4 consecutive hh per b64 write (r10-verified mapping)
    {
        const int hhw = w * 32;
        const float* bh_ = (head ? box_bh : cls_bh) + hhw;
        #pragma unroll
        for (int nt = 0; nt < 4; ++nt) {
            const int t   = nt * 32 + col;
            const int swt = (t & 7) << 3;
            #pragma unroll
            for (int g2 = 0; g2 < 4; ++g2) {
                const int hb = 8 * g2 + 4 * hi;      // C row = hb + (reg&3)
                const f32x4 bv = *(const f32x4*)(bh_ + hb);
                const float v0 = fmaxf(acc[nt][4 * g2 + 0] + bv[0], 0.f);
                const float v1 = fmaxf(acc[nt][4 * g2 + 1] + bv[1], 0.f);
                const float v2 = fmaxf(acc[nt][4 * g2 + 2] + bv[2], 0.f);
                const float v3 = fmaxf(acc[nt][4 * g2 + 3] + bv[3], 0.f);
                uint2 pk; pk.x = pkbf2(v0, v1); pk.y = pkbf2(v2, v3);
                *reinterpret_cast<uint2*>(&Hs[t * 256 + ((hhw + hb) ^ swt)]) = pk;
            }
        }
    }
    __syncthreads();

    // ---- G2 (16x16x32), r10-verified fragment/store mappings, row stride 256
    if (head == 0) {
        // cls: waves 0-4 = out-tile w across all token-tiles; Wo frags register-resident
        if (w < 5) {
            const uint16_t* Bw = wbf + WOFF_CWO + (w * 16 + r) * 256 + q * 8;
            bf16x8 bfr[8];
            #pragma unroll
            for (int kq = 0; kq < 8; ++kq) bfr[kq] = *(const bf16x8*)(Bw + kq * 32);
            const float bo_l = cls_bo[w * 16 + r];
            #pragma unroll
            for (int tt = 0; tt < 8; ++tt) {
                if (tt < NT16) {
                    const int tr  = tt * 16 + r;
                    const int swt = (tr & 7) << 3;
                    const uint16_t* hrow = &Hs[tr * 256];
                    f32x4 c = {0.f, 0.f, 0.f, 0.f};
                    #pragma unroll
                    for (int kq = 0; kq < 8; ++kq) {
                        const bf16x8 a = *(const bf16x8*)&hrow[(kq * 32 + q * 8) ^ swt];
                        c = __builtin_amdgcn_mfma_f32_16x16x32_bf16(a, bfr[kq], c, 0, 0, 0);
                    }
                    #pragma unroll
                    for (int jj = 0; jj < 4; ++jj)
                        out[((size_t)b * NTOK + n0 + tt * 16 + q * 4 + jj) * 84 + w * 16 + r]
                            = c[jj] + bo_l;
                }
            }
        }
    } else {
        // box: wave = token-tile w; decode on r<4 lanes
        if (w < NT16) {
            const uint16_t* Bw = wbf + WOFF_BWO + r * 256 + q * 8;
            const int tr  = w * 16 + r;
            const int swt = (tr & 7) << 3;
            const uint16_t* hrow = &Hs[tr * 256];
            f32x4 c = {0.f, 0.f, 0.f, 0.f};
            #pragma unroll
            for (int kq = 0; kq < 8; ++kq) {
                const bf16x8 a   = *(const bf16x8*)&hrow[(kq * 32 + q * 8) ^ swt];
                const bf16x8 bfr = *(const bf16x8*)(Bw + kq * 32);
                c = __builtin_amdgcn_mfma_f32_16x16x32_bf16(a, bfr, c, 0, 0, 0);
            }
            if (r < 4) {   // real box outs 0..3 (padded Wo rows 4..15 are zero)
                const float bo_l = box_bo[r];
                const float inv  = 1.0f / (float)dim;
                #pragma unroll
                for (int jj = 0; jj < 4; ++jj) {
                    const int t2 = w * 16 + q * 4 + jj;
                    const int p  = p0 + t2;
                    const float d = tanhf(c[jj] + bo_l);
                    float val;
                    if (r == 0)      val = ((float)(p & (dim - 1)) + 0.5f) * inv + 0.1f * d;
                    else if (r == 1) val = ((float)(p >> ls) + 0.5f) * inv + 0.1f * d;
                    else             val = exp2f(d) * inv;
                    out[((size_t)b * NTOK + n0 + t2) * 84 + 80 + r] = val;
                }
            }
        }
    }
}

extern "C" void kernel_launch(void* const* d_in, const int* in_sizes, int n_in,
                              void* d_out, int out_size, void* d_ws, size_t ws_size,
                              hipStream_t stream) {
    uint16_t* ws = (uint16_t*)d_ws;
    prep_weights<<<608, 256, 0, stream>>>(
        (const float*)d_in[5],  (const float*)d_in[7],
        (const float*)d_in[9],  (const float*)d_in[11], ws);
    // x: 22 groups of 16 = (8 tiles x 2 heads) per group; y: batch
    dim3 grid(22 * 16, 8);
    dfd_head<<<grid, 512, 0, stream>>>(
        (const float*)d_in[0], (const float*)d_in[1], (const float*)d_in[2],
        (const float*)d_in[3], (const float*)d_in[4],
        (const float*)d_in[6],  (const float*)d_in[8],
        (const float*)d_in[10], (const float*)d_in[12],
        ws, (float*)d_out);
}

// Round 15
// 110.961 us; speedup vs baseline: 2.6199x; 1.0053x over previous
//
#include <hip/hip_runtime.h>
#include <hip/hip_bf16.h>
#include <math.h>
#include <stdint.h>

#define NTOK 21824
#define NTILE128 171     // 170 full 128-token tiles + 1 tail (64 tokens)

typedef __attribute__((ext_vector_type(8)))  short bf16x8;
typedef __attribute__((ext_vector_type(4)))  float f32x4;
typedef __attribute__((ext_vector_type(16))) float f32x16;

__device__ __forceinline__ uint32_t f2bf(float f) {
    uint32_t u = __builtin_bit_cast(uint32_t, f);
    return (u + 0x7FFFu + ((u >> 16) & 1u)) >> 16;   // RNE
}
__device__ __forceinline__ uint32_t pkbf2(float lo, float hi) {
    __hip_bfloat162 h = __float22bfloat162_rn(float2{lo, hi});
    uint32_t r; __builtin_memcpy(&r, &h, 4);         // v_cvt_pk_bf16_f32
    return r;
}

// ws layout (uint16): cls_Wh @0, box_Wh @65536, cls_Wo @131072, box_Wo(pad 16x256) @151552
#define WOFF_CWH 0
#define WOFF_BWH 65536
#define WOFF_CWO 131072
#define WOFF_BWO 151552

__global__ void prep_weights(const float* __restrict__ cWh, const float* __restrict__ cWo,
                             const float* __restrict__ bWh, const float* __restrict__ bWo,
                             uint16_t* __restrict__ ws) {
    int i = blockIdx.x * 256 + threadIdx.x;
    if (i >= 155648) return;
    uint32_t v;
    if (i < 65536)       v = f2bf(cWh[i]);
    else if (i < 131072) v = f2bf(bWh[i - 65536]);
    else if (i < 151552) v = f2bf(cWo[i - 131072]);
    else { int j = i - 151552; v = (j < 1024) ? f2bf(bWo[j]) : 0u; }
    ws[i] = (uint16_t)v;
}

// Head-split block: 128 tokens x ONE head. 8 waves, 64 KB LDS overlay.
// Swizzles: Xs f^((t&31)<<3)  [G1 reads conflict-free];
//           Hs h^((t&15)<<4)  [epilogue writes conflict-free, G2 reads 2-way(free)].
__global__ __launch_bounds__(512, 4) void dfd_head(
    const float* __restrict__ fm0, const float* __restrict__ fm1,
    const float* __restrict__ fm2, const float* __restrict__ fm3,
    const float* __restrict__ fm4,
    const float* __restrict__ cls_bh, const float* __restrict__ cls_bo,
    const float* __restrict__ box_bh, const float* __restrict__ box_bo,
    const uint16_t* __restrict__ wbf,
    float* __restrict__ out)
{
    // decode (tile, head): twins (s, s+8) share id%8 -> same XCD for X L2 sharing
    const int g    = blockIdx.x;
    const int s    = g & 15;
    const int tile = (g >> 4) * 8 + (s & 7);
    const int head = s >> 3;                 // 0 = cls, 1 = box
    if (tile >= NTILE128) return;            // block-uniform

    __shared__ uint16_t LB[128 * 256];       // 64 KB overlay
    uint16_t* Xs = LB;
    uint16_t* Hs = LB;

    const int tid  = threadIdx.x;
    const int lane = tid & 63;
    const int w    = tid >> 6;               // wave 0..7
    const int r    = lane & 15;
    const int q    = lane >> 4;
    const int col  = lane & 31;
    const int hi   = lane >> 5;
    const int n0   = tile * 128;
    const int b    = blockIdx.y;

    const float* fm; int off, ls;
    if      (n0 < 16384) { fm = fm0; off = 0;     ls = 7; }
    else if (n0 < 20480) { fm = fm1; off = 16384; ls = 6; }
    else if (n0 < 21504) { fm = fm2; off = 20480; ls = 5; }
    else if (n0 < 21760) { fm = fm3; off = 21504; ls = 4; }
    else                 { fm = fm4; off = 21760; ls = 3; }
    const int dim = 1 << ls;
    const int hw  = 1 << (2 * ls);
    const int p0  = n0 - off;
    const int T   = (n0 == 21760) ? 64 : 128;   // tail tile has 64 tokens
    const int NT16 = T >> 4;

    // ---- stage: fm[b][f][p0+t] -> Xs[t][f^sw], packed b128 writes
    {
        const int t  = tid & 127;
        const int fg = tid >> 7;             // 0..3, covers 64 features
        const int sw = (t & 31) << 3;
        if (t < T) {
            const float* src = fm + (size_t)b * 256 * hw + p0 + t;
            #pragma unroll
            for (int i = 0; i < 8; ++i) {
                const int f0 = fg * 64 + i * 8;
                float x[8];
                #pragma unroll
                for (int e = 0; e < 8; ++e) x[e] = src[(size_t)(f0 + e) * hw];
                uint4 pk;
                pk.x = pkbf2(x[0], x[1]); pk.y = pkbf2(x[2], x[3]);
                pk.z = pkbf2(x[4], x[5]); pk.w = pkbf2(x[6], x[7]);
                *reinterpret_cast<uint4*>(&Xs[t * 256 + (f0 ^ sw)]) = pk;
            }
        }
    }
    __syncthreads();

    // ---- G1 (32x32x16): C[h][t]. Wave w owns hh [w*32, w*32+32) of this head.
    f32x16 acc[4];   // [nt = token 32-tile]
    {
        #pragma unroll
        for (int nt = 0; nt < 4; ++nt)
            #pragma unroll
            for (int e = 0; e < 16; ++e) acc[nt][e] = 0.f;

        const int hhw = w * 32;
        const uint16_t* Wbase = wbf + (head ? WOFF_BWH : WOFF_CWH) + hhw * 256;
        const int kh = hi * 8;
        const uint16_t* Wr = Wbase + col * 256 + kh;   // A row = hhw + col
        const int sw0 = col << 3;                      // (row&31) == col for all nt

        #pragma unroll
        for (int ks = 0; ks < 16; ++ks) {
            const bf16x8 a = *(const bf16x8*)(Wr + ks * 16);
            const int kx = (ks * 16 + kh) ^ sw0;
            #pragma unroll
            for (int nt = 0; nt < 4; ++nt) {
                const bf16x8 x = *(const bf16x8*)&Xs[(nt * 32 + col) * 256 + kx];
                acc[nt] = __builtin_amdgcn_mfma_f32_32x32x16_bf16(a, x, acc[nt], 0, 0, 0);
            }
        }
    }
    __syncthreads();   // all Xs reads done before Hs overwrites

    // ---- epilogue: bias+ReLU, pack 4 consecutive hh per b64 write
    {
        const int hhw = w * 32;
        const float* bh_ = (head ? box_bh : cls_bh) + hhw;
        #pragma unroll
        for (int nt = 0; nt < 4; ++nt) {
            const int t   = nt * 32 + col;
            const int swt = (t & 15) << 4;
            #pragma unroll
            for (int g2 = 0; g2 < 4; ++g2) {
                const int hb = 8 * g2 + 4 * hi;      // C row = hb + (reg&3)
                const f32x4 bv = *(const f32x4*)(bh_ + hb);
                const float v0 = fmaxf(acc[nt][4 * g2 + 0] + bv[0], 0.f);
                const float v1 = fmaxf(acc[nt][4 * g2 + 1] + bv[1], 0.f);
                const float v2 = fmaxf(acc[nt][4 * g2 + 2] + bv[2], 0.f);
                const float v3 = fmaxf(acc[nt][4 * g2 + 3] + bv[3], 0.f);
                uint2 pk; pk.x = pkbf2(v0, v1); pk.y = pkbf2(v2, v3);
                *reinterpret_cast<uint2*>(&Hs[t * 256 + ((hhw + hb) ^ swt)]) = pk;
            }
        }
    }
    __syncthreads();

    // ---- G2 (16x16x32)
    if (head == 0) {
        if (w < 5) {
            const uint16_t* Bw = wbf + WOFF_CWO + (w * 16 + r) * 256 + q * 8;
            bf16x8 bfr[8];
            #pragma unroll
            for (int kq = 0; kq < 8; ++kq) bfr[kq] = *(const bf16x8*)(Bw + kq * 32);
            const float bo_l = cls_bo[w * 16 + r];
            #pragma unroll
            for (int tt = 0; tt < 8; ++tt) {
                if (tt < NT16) {
                    const int tr  = tt * 16 + r;
                    const int swt = (tr & 15) << 4;   // == r<<4
                    const uint16_t* hrow = &Hs[tr * 256];
                    f32x4 c = {0.f, 0.f, 0.f, 0.f};
                    #pragma unroll
                    for (int kq = 0; kq < 8; ++kq) {
                        const bf16x8 a = *(const bf16x8*)&hrow[(kq * 32 + q * 8) ^ swt];
                        c = __builtin_amdgcn_mfma_f32_16x16x32_bf16(a, bfr[kq], c, 0, 0, 0);
                    }
                    #pragma unroll
                    for (int jj = 0; jj < 4; ++jj)
                        out[((size_t)b * NTOK + n0 + tt * 16 + q * 4 + jj) * 84 + w * 16 + r]
                            = c[jj] + bo_l;
                }
            }
        }
    } else {
        if (w < NT16) {
            const uint16_t* Bw = wbf + WOFF_BWO + r * 256 + q * 8;
            const int tr  = w * 16 + r;
            const int swt = (tr & 15) << 4;
            const uint16_t* hrow = &Hs[tr * 256];
            f32x4 c = {0.f, 0.f, 0.f, 0.f};
            #pragma unroll
            for (int kq = 0; kq < 8; ++kq) {
                const bf16x8 a   = *(const bf16x8*)&hrow[(kq * 32 + q * 8) ^ swt];
                const bf16x8 bfr = *(const bf16x8*)(Bw + kq * 32);
                c = __builtin_amdgcn_mfma_f32_16x16x32_bf16(a, bfr, c, 0, 0, 0);
            }
            if (r < 4) {
                const float bo_l = box_bo[r];
                const float inv  = 1.0f / (float)dim;
                #pragma unroll
                for (int jj = 0; jj < 4; ++jj) {
                    const int t2 = w * 16 + q * 4 + jj;
                    const int p  = p0 + t2;
                    const float d = tanhf(c[jj] + bo_l);
                    float val;
                    if (r == 0)      val = ((float)(p & (dim - 1)) + 0.5f) * inv + 0.1f * d;
                    else if (r == 1) val = ((float)(p >> ls) + 0.5f) * inv + 0.1f * d;
                    else             val = exp2f(d) * inv;
                    out[((size_t)b * NTOK + n0 + t2) * 84 + 80 + r] = val;
                }
            }
        }
    }
}

extern "C" void kernel_launch(void* const* d_in, const int* in_sizes, int n_in,
                              void* d_out, int out_size, void* d_ws, size_t ws_size,
                              hipStream_t stream) {
    uint16_t* ws = (uint16_t*)d_ws;
    prep_weights<<<608, 256, 0, stream>>>(
        (const float*)d_in[5],  (const float*)d_in[7],
        (const float*)d_in[9],  (const float*)d_in[11], ws);
    dim3 grid(22 * 16, 8);
    dfd_head<<<grid, 512, 0, stream>>>(
        (const float*)d_in[0], (const float*)d_in[1], (const float*)d_in[2],
        (const float*)d_in[3], (const float*)d_in[4],
        (const float*)d_in[6],  (const float*)d_in[8],
        (const float*)d_in[10], (const float*)d_in[12],
        ws, (float*)d_out);
}